// Round 7
// baseline (31.704 us; speedup 1.0000x reference)
//
#include <hip/hip_runtime.h>
#include <math.h>

#define DIM  4096
#define KOUT 10
#define BATCH 4096
#define WPB  4       // waves per block; each wave owns one batch row + 8KB LDS slice

// XOR-swizzle on linear LDS float index (verified R1/R4/R6): XOR row bits
// (6-8) into 16B-granule slot bits (2-4). Involution; row-contiguous b128
// accesses and strided-64 b32 accesses both land at the bank floor.
__device__ __forceinline__ int swzAddr(int lin) {
    return lin ^ (((lin >> 6) & 7) << 2);
}

__device__ __forceinline__ float rlane(float v, int lane) {
    return __int_as_float(__builtin_amdgcn_readlane(__float_as_int(v), lane));
}

// Drain all pending LDS ops (verified necessary in R6). Same-wave LDS WAR:
// ds_write may clobber rows whose prior ds_read hasn't returned yet; the
// compiler only inserts lgkmcnt waits before USES of loaded data, never
// before subsequent ds_writes. sched_barrier pins DS ops to the fence.
__device__ __forceinline__ void ldsFence() {
    __builtin_amdgcn_sched_barrier(0);
    asm volatile("s_waitcnt lgkmcnt(0)" ::: "memory");
    __builtin_amdgcn_sched_barrier(0);
}

// One RY layer on reg-bit K via 3-fma lifting shears (verified R4/R6).
// t = tan(phi/2), s = sin(phi) for rotation angle phi (or -cot/-sin => -R).
template<int K>
__device__ __forceinline__ void liftLayer(float r[64], float t, float s) {
#pragma unroll
    for (int m = 0; m < 32; ++m) {
        const int i0 = ((m >> K) << (K + 1)) | (m & ((1 << K) - 1));
        const int i1 = i0 | (1 << K);
        float a = r[i0], b = r[i1];
        float a1 = fmaf(-t, b, a);
        float b1 = fmaf(s, a1, b);
        r[i1] = b1;
        r[i0] = fmaf(-t, b1, a1);
    }
}

// 8 KB time-shared lane<->reg transpose with WAR fences (verified R6).
// r_new[j]@lane l = r_old[l]@lane j.
__device__ __forceinline__ void transpose64(float r[64], float* lds, int l) {
    float tmp[32];
    ldsFence();                 // vs. previous transpose's phase-1 reads
    if (l < 32) {
#pragma unroll
        for (int e4 = 0; e4 < 16; ++e4)
            *reinterpret_cast<float4*>(&lds[swzAddr(l * 64 + e4 * 4)]) =
                make_float4(r[e4 * 4 + 0], r[e4 * 4 + 1],
                            r[e4 * 4 + 2], r[e4 * 4 + 3]);
    }
#pragma unroll
    for (int j = 0; j < 32; ++j)
        tmp[j] = lds[swzAddr(j * 64 + l)];          // = r_old[l]@lane j, j<32
    ldsFence();                 // vs. phase-0 reads just issued
    if (l >= 32) {
#pragma unroll
        for (int e4 = 0; e4 < 16; ++e4)
            *reinterpret_cast<float4*>(&lds[swzAddr((l - 32) * 64 + e4 * 4)]) =
                make_float4(r[e4 * 4 + 0], r[e4 * 4 + 1],
                            r[e4 * 4 + 2], r[e4 * 4 + 3]);
    }
#pragma unroll
    for (int j = 0; j < 32; ++j)
        r[32 + j] = lds[swzAddr(j * 64 + l)];       // = r_old[l]@lane 32+j
#pragma unroll
    for (int j = 0; j < 32; ++j)
        r[j] = tmp[j];
}

__global__ __launch_bounds__(256, 4) void vqc_kernel(
        const float* __restrict__ x,
        const float* __restrict__ theta,
        float* __restrict__ out)
{
    __shared__ __align__(16) float ldsAll[WPB * 2048];   // 32 KB, private slices
    const int tid = threadIdx.x;
    const int l   = tid & 63;
    const int wid = tid >> 6;
    const int b   = blockIdx.x * WPB + wid;
    float* lds = ldsAll + wid * 2048;

    // Gate params for lifting. RY(theta) rotates by phi = theta/2:
    // t = tan(theta/4), s = sin(theta/2); alt branch -R(phi) keeps |t|<=1.
    float th = theta[l < 24 ? l : 0];
    float qh = 0.25f * th;
    float sq = sinf(qh), cq = cosf(qh);
    float sfull = 2.f * sq * cq;                       // sin(theta/2)
    float tt, ss;
    if (fabsf(sq) <= fabsf(cq)) { tt = sq / cq;  ss = sfull;  }
    else                        { tt = -cq / sq; ss = -sfull; }

    // ---- direct load into pass-1 layout: r[j] = x[b*DIM + l*64 + j] ----
    float r[64];
    const float4* x4 = reinterpret_cast<const float4*>(x + (size_t)b * DIM + l * 64);
#pragma unroll
    for (int e4 = 0; e4 < 16; ++e4) {
        const float4 w = x4[e4];
        r[e4 * 4 + 0] = w.x; r[e4 * 4 + 1] = w.y;
        r[e4 * 4 + 2] = w.z; r[e4 * 4 + 3] = w.w;
    }

    // ---- pass 1: qubits 0-5, layer 1 (thread l holds d = l*64 + j) ----
    liftLayer<0>(r, rlane(tt, 0), rlane(ss, 0));
    liftLayer<1>(r, rlane(tt, 1), rlane(ss, 1));
    liftLayer<2>(r, rlane(tt, 2), rlane(ss, 2));
    liftLayer<3>(r, rlane(tt, 3), rlane(ss, 3));
    liftLayer<4>(r, rlane(tt, 4), rlane(ss, 4));
    liftLayer<5>(r, rlane(tt, 5), rlane(ss, 5));

    transpose64(r, lds, l);                  // r[j] = state[(j<<6)|l]

    // ---- pass 2: qubits 6-11, layer 1 ----
    liftLayer<0>(r, rlane(tt, 6),  rlane(ss, 6));
    liftLayer<1>(r, rlane(tt, 7),  rlane(ss, 7));
    liftLayer<2>(r, rlane(tt, 8),  rlane(ss, 8));
    liftLayer<3>(r, rlane(tt, 9),  rlane(ss, 9));
    liftLayer<4>(r, rlane(tt, 10), rlane(ss, 10));
    liftLayer<5>(r, rlane(tt, 11), rlane(ss, 11));

    // CZ diagonal (verified): lane bits = qubits 0-5, reg bits e = qubits 6-11
    {
        int f  = __popc(l & (l >> 1) & 0x1F) & 1;  // pairs among qubits 0-5
        int l5 = (l >> 5) & 1, l0 = l & 1;
        float sg0 = f              ? -1.f : 1.f;
        float sg1 = (f ^ l5)       ? -1.f : 1.f;   // e0=1: pair (5,6)
        float sg2 = (f ^ l0)       ? -1.f : 1.f;   // e5=1: pair (0,11)
        float sg3 = (f ^ l5 ^ l0)  ? -1.f : 1.f;
#pragma unroll
        for (int e = 0; e < 64; ++e) {
            const int Ce  = __popc(e & (e >> 1) & 0x1F) & 1;  // pairs among 6-11
            const int sel = (e & 1) | (((e >> 5) & 1) << 1);
            float sgn;
            if      (sel == 0) sgn = sg0;
            else if (sel == 1) sgn = sg1;
            else if (sel == 2) sgn = sg2;
            else               sgn = sg3;
            r[e] *= (Ce ? -sgn : sgn);
        }
    }

    // ---- layer 2 on qubits 6-11 (theta[18..23]) ----
    liftLayer<0>(r, rlane(tt, 18), rlane(ss, 18));
    liftLayer<1>(r, rlane(tt, 19), rlane(ss, 19));
    liftLayer<2>(r, rlane(tt, 20), rlane(ss, 20));
    liftLayer<3>(r, rlane(tt, 21), rlane(ss, 21));
    liftLayer<4>(r, rlane(tt, 22), rlane(ss, 22));
    liftLayer<5>(r, rlane(tt, 23), rlane(ss, 23));

    transpose64(r, lds, l);                  // r[j] = state[l*64 + j]

    // ---- pass 3: qubits 0-5, layer 2 (theta[12..17]) ----
    liftLayer<0>(r, rlane(tt, 12), rlane(ss, 12));
    liftLayer<1>(r, rlane(tt, 13), rlane(ss, 13));
    liftLayer<2>(r, rlane(tt, 14), rlane(ss, 14));
    liftLayer<3>(r, rlane(tt, 15), rlane(ss, 15));
    liftLayer<4>(r, rlane(tt, 16), rlane(ss, 16));
    liftLayer<5>(r, rlane(tt, 17), rlane(ss, 17));

    // ---- measurement: d = l*64 + j; qubit k<6 = j-bit k, qubits 6-9 = l-bits 0-3.
    // Square in place, then halving tree extracting each bit's masked sum.
    float v0 = 0.f, v1 = 0.f, v2 = 0.f, v3 = 0.f, v4 = 0.f;
#pragma unroll
    for (int j = 0; j < 64; ++j) r[j] = r[j] * r[j];
    float q32[32];
#pragma unroll
    for (int m = 0; m < 32; ++m) { v0 += r[2*m+1]; q32[m] = r[2*m] + r[2*m+1]; }
    float q16[16];
#pragma unroll
    for (int m = 0; m < 16; ++m) { v1 += q32[2*m+1]; q16[m] = q32[2*m] + q32[2*m+1]; }
    float q8[8];
#pragma unroll
    for (int m = 0; m < 8; ++m)  { v2 += q16[2*m+1]; q8[m] = q16[2*m] + q16[2*m+1]; }
    float q4[4];
#pragma unroll
    for (int m = 0; m < 4; ++m)  { v3 += q8[2*m+1]; q4[m] = q8[2*m] + q8[2*m+1]; }
    float q2[2];
#pragma unroll
    for (int m = 0; m < 2; ++m)  { v4 += q4[2*m+1]; q2[m] = q4[2*m] + q4[2*m+1]; }
    const float v5   = q2[1];
    const float psum = q2[0] + q2[1];

    float v[10];
    v[0] = v0; v[1] = v1; v[2] = v2; v[3] = v3; v[4] = v4; v[5] = v5;
    v[6] = (l & 1) ? psum : 0.f;
    v[7] = (l & 2) ? psum : 0.f;
    v[8] = (l & 4) ? psum : 0.f;
    v[9] = (l & 8) ? psum : 0.f;

#pragma unroll
    for (int k = 0; k < 10; ++k) {
        float t = v[k];
#pragma unroll
        for (int off = 32; off >= 1; off >>= 1)
            t += __shfl_xor(t, off, 64);
        v[k] = t;
    }

    if (l == 0) {
#pragma unroll
        for (int k = 0; k < KOUT; ++k) out[b * KOUT + k] = v[k];
    }
}

extern "C" void kernel_launch(void* const* d_in, const int* in_sizes, int n_in,
                              void* d_out, int out_size, void* d_ws, size_t ws_size,
                              hipStream_t stream) {
    const float* x     = (const float*)d_in[0];
    const float* theta = (const float*)d_in[1];
    float* out         = (float*)d_out;
    vqc_kernel<<<BATCH / WPB, 256, 0, stream>>>(x, theta, out);
}

// Round 8
// 27.311 us; speedup vs baseline: 1.1609x; 1.1609x over previous
//
#include <hip/hip_runtime.h>
#include <math.h>

#define DIM  4096
#define KOUT 10
#define BATCH 4096

typedef float float2v __attribute__((ext_vector_type(2)));

// XOR-swizzle on linear LDS float index (verified R1/R4/R6): XOR row bits
// (6-8) into 16B-granule slot bits (2-4). Involution; row-contiguous b128
// accesses and strided-64 b32 accesses both land at the bank floor.
__device__ __forceinline__ int swzAddr(int lin) {
    return lin ^ (((lin >> 6) & 7) << 2);
}

__device__ __forceinline__ float rlane(float v, int lane) {
    return __int_as_float(__builtin_amdgcn_readlane(__float_as_int(v), lane));
}

// Drain all pending LDS ops (verified necessary in R6). Same-wave LDS WAR:
// ds_write may clobber rows whose prior ds_read hasn't returned yet; the
// compiler only inserts lgkmcnt waits before USES of loaded data, never
// before subsequent ds_writes. sched_barrier pins DS ops to the fence.
__device__ __forceinline__ void ldsFence() {
    __builtin_amdgcn_sched_barrier(0);
    asm volatile("s_waitcnt lgkmcnt(0)" ::: "memory");
    __builtin_amdgcn_sched_barrier(0);
}

// Packed RY lifting layer on scalar state bit KP+1 (packed-reg bit KP).
// Both float2 components undergo the same (t,s) rotation -> v_pk_fma_f32.
// t = tan(phi/2), s = sin(phi) (or -cot/-sin => -R; sign cancels in probs).
template<int KP>
__device__ __forceinline__ void liftPk(float2v r2[32], float t, float s) {
    const float2v tv = { -t, -t };
    const float2v sv = {  s,  s };
#pragma unroll
    for (int m = 0; m < 16; ++m) {
        const int i0 = ((m >> KP) << (KP + 1)) | (m & ((1 << KP) - 1));
        const int i1 = i0 | (1 << KP);
        float2v a = r2[i0], b = r2[i1];
        float2v a1 = __builtin_elementwise_fma(tv, b, a);
        float2v b1 = __builtin_elementwise_fma(sv, a1, b);
        r2[i1] = b1;
        r2[i0] = __builtin_elementwise_fma(tv, b1, a1);
    }
}

// Scalar RY lifting layer on state bit 0 (within each float2).
__device__ __forceinline__ void liftIntra(float2v r2[32], float t, float s) {
#pragma unroll
    for (int m = 0; m < 32; ++m) {
        float a = r2[m].x, b = r2[m].y;
        float a1 = fmaf(-t, b, a);
        float b1 = fmaf(s, a1, b);
        r2[m].x = fmaf(-t, b1, a1);
        r2[m].y = b1;
    }
}

// 8 KB time-shared lane<->reg transpose with WAR fences (verified R6).
// Scalar semantics: r_new[j]@lane l = r_old[l]@lane j; r2[m] = scalars {2m, 2m+1}.
__device__ __forceinline__ void transpose64(float2v r2[32], float* lds, int l) {
    float tmp[32];
    ldsFence();                 // vs. previous transpose's phase-1 reads
    if (l < 32) {
#pragma unroll
        for (int e4 = 0; e4 < 16; ++e4)
            *reinterpret_cast<float4*>(&lds[swzAddr(l * 64 + e4 * 4)]) =
                make_float4(r2[2 * e4].x, r2[2 * e4].y,
                            r2[2 * e4 + 1].x, r2[2 * e4 + 1].y);
    }
#pragma unroll
    for (int j = 0; j < 32; ++j)
        tmp[j] = lds[swzAddr(j * 64 + l)];          // new scalars 0..31
    ldsFence();                 // vs. phase-0 reads just issued
    if (l >= 32) {
#pragma unroll
        for (int e4 = 0; e4 < 16; ++e4)
            *reinterpret_cast<float4*>(&lds[swzAddr((l - 32) * 64 + e4 * 4)]) =
                make_float4(r2[2 * e4].x, r2[2 * e4].y,
                            r2[2 * e4 + 1].x, r2[2 * e4 + 1].y);
    }
#pragma unroll
    for (int m = 0; m < 16; ++m) {                  // new scalars 32..63
        float2v w;
        w.x = lds[swzAddr((2 * m) * 64 + l)];
        w.y = lds[swzAddr((2 * m + 1) * 64 + l)];
        r2[16 + m] = w;
    }
#pragma unroll
    for (int m = 0; m < 16; ++m) {
        float2v w; w.x = tmp[2 * m]; w.y = tmp[2 * m + 1];
        r2[m] = w;
    }
}

__global__ __launch_bounds__(64) void vqc_kernel(
        const float* __restrict__ x,
        const float* __restrict__ theta,
        float* __restrict__ out)
{
    __shared__ __align__(16) float lds[2048];   // 8 KB
    const int l = threadIdx.x;   // one wave per block, one batch row per block
    const int b = blockIdx.x;

    // Gate params for lifting. RY(theta) rotates by phi = theta/2:
    // t = tan(theta/4), s = sin(theta/2); alt branch -R(phi) keeps |t|<=1.
    float th = theta[l < 24 ? l : 0];
    float qh = 0.25f * th;
    float sq = sinf(qh), cq = cosf(qh);
    float sfull = 2.f * sq * cq;                       // sin(theta/2)
    float tt, ss;
    if (fabsf(sq) <= fabsf(cq)) { tt = sq / cq;  ss = sfull;  }
    else                        { tt = -cq / sq; ss = -sfull; }

    // ---- direct load into pass-1 layout: scalar r[j] = x[b*DIM + l*64 + j] ----
    float2v r2[32];
    const float4* x4 = reinterpret_cast<const float4*>(x + (size_t)b * DIM + l * 64);
#pragma unroll
    for (int e4 = 0; e4 < 16; ++e4) {
        const float4 w = x4[e4];
        float2v lo; lo.x = w.x; lo.y = w.y;
        float2v hi; hi.x = w.z; hi.y = w.w;
        r2[2 * e4]     = lo;
        r2[2 * e4 + 1] = hi;
    }

    // ---- pass 1: qubits 0-5, layer 1 (scalar bit k = qubit k) ----
    liftIntra (r2, rlane(tt, 0), rlane(ss, 0));
    liftPk<0>(r2, rlane(tt, 1), rlane(ss, 1));
    liftPk<1>(r2, rlane(tt, 2), rlane(ss, 2));
    liftPk<2>(r2, rlane(tt, 3), rlane(ss, 3));
    liftPk<3>(r2, rlane(tt, 4), rlane(ss, 4));
    liftPk<4>(r2, rlane(tt, 5), rlane(ss, 5));

    transpose64(r2, lds, l);                 // scalar bit k = qubit 6+k

    // ---- pass 2: qubits 6-11, layer 1 ----
    liftIntra (r2, rlane(tt, 6),  rlane(ss, 6));
    liftPk<0>(r2, rlane(tt, 7),  rlane(ss, 7));
    liftPk<1>(r2, rlane(tt, 8),  rlane(ss, 8));
    liftPk<2>(r2, rlane(tt, 9),  rlane(ss, 9));
    liftPk<3>(r2, rlane(tt, 10), rlane(ss, 10));
    liftPk<4>(r2, rlane(tt, 11), rlane(ss, 11));

    // CZ diagonal (verified R6): lane bits = qubits 0-5, scalar reg bits e = 6-11
    {
        int f  = __popc(l & (l >> 1) & 0x1F) & 1;  // pairs among qubits 0-5
        int l5 = (l >> 5) & 1, l0 = l & 1;
        float sg0 = f              ? -1.f : 1.f;
        float sg1 = (f ^ l5)       ? -1.f : 1.f;   // e0=1: pair (5,6)
        float sg2 = (f ^ l0)       ? -1.f : 1.f;   // e5=1: pair (0,11)
        float sg3 = (f ^ l5 ^ l0)  ? -1.f : 1.f;
#pragma unroll
        for (int e = 0; e < 64; ++e) {
            const int Ce  = __popc(e & (e >> 1) & 0x1F) & 1;  // pairs among 6-11
            const int sel = (e & 1) | (((e >> 5) & 1) << 1);
            float sgn;
            if      (sel == 0) sgn = sg0;
            else if (sel == 1) sgn = sg1;
            else if (sel == 2) sgn = sg2;
            else               sgn = sg3;
            const float m = Ce ? -sgn : sgn;
            if (e & 1) r2[e >> 1].y *= m;
            else       r2[e >> 1].x *= m;
        }
    }

    // ---- layer 2 on qubits 6-11 (theta[18..23]) ----
    liftIntra (r2, rlane(tt, 18), rlane(ss, 18));
    liftPk<0>(r2, rlane(tt, 19), rlane(ss, 19));
    liftPk<1>(r2, rlane(tt, 20), rlane(ss, 20));
    liftPk<2>(r2, rlane(tt, 21), rlane(ss, 21));
    liftPk<3>(r2, rlane(tt, 22), rlane(ss, 22));
    liftPk<4>(r2, rlane(tt, 23), rlane(ss, 23));

    transpose64(r2, lds, l);                 // scalar bit k = qubit k

    // ---- pass 3: qubits 0-5, layer 2 (theta[12..17]) ----
    liftIntra (r2, rlane(tt, 12), rlane(ss, 12));
    liftPk<0>(r2, rlane(tt, 13), rlane(ss, 13));
    liftPk<1>(r2, rlane(tt, 14), rlane(ss, 14));
    liftPk<2>(r2, rlane(tt, 15), rlane(ss, 15));
    liftPk<3>(r2, rlane(tt, 16), rlane(ss, 16));
    liftPk<4>(r2, rlane(tt, 17), rlane(ss, 17));

    // ---- measurement (tree verified R7): d = l*64 + j; qubit k<6 = j-bit k,
    //      qubits 6-9 = l-bits 0-3. Square in place (pk), then halving tree.
#pragma unroll
    for (int m = 0; m < 32; ++m) r2[m] *= r2[m];

    float v0 = 0.f, v1 = 0.f, v2 = 0.f, v3 = 0.f, v4 = 0.f;
    float q32[32];
#pragma unroll
    for (int m = 0; m < 32; ++m) { v0 += r2[m].y; q32[m] = r2[m].x + r2[m].y; }
    float q16[16];
#pragma unroll
    for (int m = 0; m < 16; ++m) { v1 += q32[2*m+1]; q16[m] = q32[2*m] + q32[2*m+1]; }
    float q8[8];
#pragma unroll
    for (int m = 0; m < 8; ++m)  { v2 += q16[2*m+1]; q8[m] = q16[2*m] + q16[2*m+1]; }
    float q4[4];
#pragma unroll
    for (int m = 0; m < 4; ++m)  { v3 += q8[2*m+1]; q4[m] = q8[2*m] + q8[2*m+1]; }
    float q2[2];
#pragma unroll
    for (int m = 0; m < 2; ++m)  { v4 += q4[2*m+1]; q2[m] = q4[2*m] + q4[2*m+1]; }
    const float v5   = q2[1];
    const float psum = q2[0] + q2[1];

    float v[10];
    v[0] = v0; v[1] = v1; v[2] = v2; v[3] = v3; v[4] = v4; v[5] = v5;
    v[6] = (l & 1) ? psum : 0.f;
    v[7] = (l & 2) ? psum : 0.f;
    v[8] = (l & 4) ? psum : 0.f;
    v[9] = (l & 8) ? psum : 0.f;

#pragma unroll
    for (int k = 0; k < 10; ++k) {
        float t = v[k];
#pragma unroll
        for (int off = 32; off >= 1; off >>= 1)
            t += __shfl_xor(t, off, 64);
        v[k] = t;
    }

    if (l == 0) {
#pragma unroll
        for (int k = 0; k < KOUT; ++k) out[b * KOUT + k] = v[k];
    }
}

extern "C" void kernel_launch(void* const* d_in, const int* in_sizes, int n_in,
                              void* d_out, int out_size, void* d_ws, size_t ws_size,
                              hipStream_t stream) {
    const float* x     = (const float*)d_in[0];
    const float* theta = (const float*)d_in[1];
    float* out         = (float*)d_out;
    vqc_kernel<<<BATCH, 64, 0, stream>>>(x, theta, out);
}